// Round 5
// baseline (1887.897 us; speedup 1.0000x reference)
//
#include <hip/hip_runtime.h>

// LIF fused kernel, Round 5 — sparse accumulation, barrier-free t-loop.
// (Round 4 design; macro token-capture bug fixed by using lambdas.)
//
// Inputs fp32: spikes [T,B,F] exact {0,1} (~10% dense), W [F,F].
// Outputs fp32 concat: z_last, v, i (each [B,F]).
//
// Insight: xs depends only on input spikes (not state) and spikes are {0,1},
// so x[t,b,g] = sum over active f of W[g][f] — an EXACT fp32 sparse sum
// (~51 adds vs 1024 MACs dense; no W-splitting needed; only summation-order
// noise ~1e-7 vs the np reference).
//
// Layout: 256 blocks x 512 thr (8 waves). Block = b-tile of 8 rows x 64 g.
// Wave owns 1 row x 64 g: lane = g. W slice [512 f][64 g] fp32 transposed
// into LDS once (reads are lane-consecutive -> 2-way bank alias = free).
// Per t (no barriers, waves free-run):
//   - spike row prefetched 2t ahead (8 coalesced dwords)
//   - ballot -> 8 masks; mbcnt rank-compaction scatters active-f LDS word-
//     offsets into a per-wave double-buffered list (pad to 8 with zero-row)
//   - consume: ping-pong pairs of 4-offset chunks; W-values for the next
//     pair load while the current pair accumulates (hides ds_read latency)
//   - LIF update in registers (v, i, z per lane)
// b_tile = bid&31 -> all 8 g-blocks of a tile share an XCD (bid%8) so each
// spike row is HBM-fetched once, L2-served 8x.

#define T_STEPS 1024
#define B_DIM   256
#define F_DIM   512
#define BF      (B_DIM * F_DIM)
#define GBLK    64
#define ROWS    8
#define ZIDX    (512 * GBLK)          // zero-row word index (pad target)
#define LCAP    128                   // list slots; P<=~96 padded to <=104
#define WL_WORDS (513 * GBLK)         // 513 rows x 64 g

__global__ __launch_bounds__(512, 1)
void lif_sparse(const float* __restrict__ spikes,
                const float* __restrict__ W,
                float* __restrict__ out)
{
    __shared__ float    Wl[WL_WORDS];             // 131328 B
    __shared__ __align__(16) unsigned lists[ROWS * 2 * LCAP];  // 8192 B

    const int tid  = threadIdx.x;
    const unsigned lane = tid & 63u;
    const int wav  = tid >> 6;
    const int bid  = blockIdx.x;
    const int bt   = bid & 31;          // b-tile; bid%8 == bt%8 -> same XCD
    const int gb   = bid >> 5;          // 0..7
    const int g0   = gb * GBLK;
    const int row  = bt * ROWS + wav;

    // ---- stage W slice (transposed): Wl[f*64 + gi] = W[g0+gi][f]
    {
        const int gi = tid & 63;
        const int fc = tid >> 6;        // 8 chunks of 64 f
        const float* wrow = W + (size_t)(g0 + gi) * F_DIM + fc * 64;
        #pragma unroll
        for (int u = 0; u < 16; ++u) {
            float4 wv = *(const float4*)(wrow + u * 4);
            const int f = fc * 64 + u * 4;
            Wl[(f + 0) * GBLK + gi] = wv.x;
            Wl[(f + 1) * GBLK + gi] = wv.y;
            Wl[(f + 2) * GBLK + gi] = wv.z;
            Wl[(f + 3) * GBLK + gi] = wv.w;
        }
        if (tid < GBLK) Wl[ZIDX + tid] = 0.f;   // zero row for padding
    }
    __syncthreads();   // the only barrier in the kernel

    unsigned* lb0 = lists + wav * (2 * LCAP);
    unsigned* lb1 = lb0 + LCAP;

    const size_t rowbase = (size_t)row * F_DIM + lane;
    const unsigned vbase = lane * GBLK;   // word-offset contribution of lane

    float sp0[8], sp1[8];
    auto loadsp = [&](float* d, int t) {
        const float* p = spikes + (size_t)t * BF + rowbase;
        #pragma unroll
        for (int j = 0; j < 8; ++j) d[j] = p[j * 64];
    };

    // decode: rank-compacted scatter of active-f word offsets (f*64)
    auto decode = [&](unsigned* lb, const float* sp) -> int {
        int cnt = 0;
        #pragma unroll
        for (int j = 0; j < 8; ++j) {
            bool act = (__float_as_uint(sp[j]) != 0u);
            unsigned long long m = __ballot(act);
            unsigned rank = __builtin_amdgcn_mbcnt_hi(
                (unsigned)(m >> 32), __builtin_amdgcn_mbcnt_lo((unsigned)m, 0u));
            if (act) lb[cnt + rank] = (unsigned)(j * (64 * GBLK)) + vbase;
            cnt += (int)__popcll(m);
        }
        int P8 = (cnt + 7) & ~7;
        if (P8 == 0) P8 = 8;
        const int npad = P8 - cnt;
        if ((int)lane < npad) lb[cnt + (int)lane] = ZIDX;
        return P8;
    };

    // load 8 W-values for the two offset-quads (lambdas, not macros: a macro
    // parameter here would capture the token `w` inside `oB.w` — that was
    // Round 4's compile failure)
    auto ldw = [&](float* d, uint4 oA, uint4 oB) {
        d[0] = Wl[oA.x + lane]; d[1] = Wl[oA.y + lane];
        d[2] = Wl[oA.z + lane]; d[3] = Wl[oA.w + lane];
        d[4] = Wl[oB.x + lane]; d[5] = Wl[oB.y + lane];
        d[6] = Wl[oB.z + lane]; d[7] = Wl[oB.w + lane];
    };

    // consume: ping-pong pairs; next pair's W-reads in flight during adds
    auto consume = [&](const unsigned* lb, int P8) -> float {
        const uint4* ch = (const uint4*)lb;
        const int pairs = P8 >> 3;
        float a0 = 0.f, a1 = 0.f, a2 = 0.f, a3 = 0.f;
        float wX[8], wY[8];
        auto acc = [&](const float* d) {
            a0 += d[0]; a1 += d[1]; a2 += d[2]; a3 += d[3];
            a0 += d[4]; a1 += d[5]; a2 += d[6]; a3 += d[7];
        };
        ldw(wX, ch[0], ch[1]);
        bool pendX = true;
        for (int i = 1; i < pairs; ++i) {
            if (pendX) { ldw(wY, ch[2 * i], ch[2 * i + 1]); acc(wX); }
            else       { ldw(wX, ch[2 * i], ch[2 * i + 1]); acc(wY); }
            pendX = !pendX;
        }
        if (pendX) { acc(wX); } else { acc(wY); }
        return (a0 + a1) + (a2 + a3);
    };

    // ---- LIF state (per lane: b=row, g=g0+lane)
    float v = 0.f, cu = 0.f, zf = 0.f;
    auto lif = [&](float x) {
        float vdec = v + 0.1f * ((0.0f - v) + cu);   // DT*TAU_MEM_INV = 0.1
        float idec = cu - 0.2f * cu;                  // DT*TAU_SYN_INV = 0.2
        bool  spk  = (vdec - 1.0f) > 0.0f;            // heaviside
        zf = spk ? 1.0f : 0.0f;
        v  = spk ? 0.0f : vdec;                       // V_RESET = 0
        cu = idec + x;
    };

    // ---- prologue: buf0 = list(0); sp1 = spikes(1); sp0 = spikes(2)
    loadsp(sp0, 0);
    int P0 = decode(lb0, sp0);
    loadsp(sp1, 1);
    loadsp(sp0, 2);

    for (int t = 0; t < T_STEPS; t += 2) {
        // iter A: decode t+1 early (its scatter drains under consume(t))
        int P1 = decode(lb1, sp1);
        loadsp(sp1, min(t + 3, T_STEPS - 1));
        lif(consume(lb0, P0));
        // iter B
        P0 = decode(lb0, sp0);
        loadsp(sp0, min(t + 4, T_STEPS - 1));
        lif(consume(lb1, P1));
    }

    // ---- epilogue
    const size_t oidx = (size_t)row * F_DIM + g0 + lane;
    out[oidx]          = zf;
    out[BF + oidx]     = v;
    out[2 * BF + oidx] = cu;
}

extern "C" void kernel_launch(void* const* d_in, const int* in_sizes, int n_in,
                              void* d_out, int out_size, void* d_ws, size_t ws_size,
                              hipStream_t stream)
{
    const float* spikes = (const float*)d_in[0];   // [T,B,F] fp32
    const float* W      = (const float*)d_in[1];   // [F,F]   fp32
    float* out          = (float*)d_out;           // [3,B,F] fp32

    lif_sparse<<<dim3(256), dim3(512), 0, stream>>>(spikes, W, out);
}

// Round 6
// 1836.806 us; speedup vs baseline: 1.0278x; 1.0278x over previous
//
#include <hip/hip_runtime.h>

// LIF fused kernel, Round 6 — sparse accumulation, dual-t-stream 3-deep pipeline.
//
// Inputs fp32: spikes [T,B,F] exact {0,1} (~10% dense), W [F,F].
// Outputs fp32 concat: z_last, v, i (each [B,F]).
//
// x[t,b,g] = sum over active f of W[g][f] — exact fp32 sparse sum.
// R5 post-mortem: 1460 us, VALUBusy 38% -> ~60% of time was exposed LDS
// latency (list-chunk reads consumed same-iteration; only 2 waves/SIMD).
// R6: consume TWO t-steps at once (independent until the tiny LIF update,
// doubling independent LDS streams) and pipeline 3-deep:
//   chunk offsets for i+1 in flight | W-reads for i in flight | acc i-1.
//
// Layout: 256 blocks x 512 thr (8 waves). Block = b-tile of 8 rows x 64 g.
// Wave owns 1 row x 64 g: lane = g. W slice [512 f][64 g] fp32 in LDS
// (reads lane-consecutive -> 2-way bank alias = free; R5 measured 0 conflicts).
// Per wave: 4 list buffers (double-buffered PAIRS of t-steps); lists of a
// pair are padded (with a zero-row index) to a common chunk count so the
// dual consume loop is uniform.

#define T_STEPS 1024
#define B_DIM   256
#define F_DIM   512
#define BF      (B_DIM * F_DIM)
#define GBLK    64
#define ROWS    8
#define ZIDX    (512 * GBLK)          // zero-row word index (pad target)
#define LCAP    128                   // entries per buffer (P<=~90 padded <=92)
#define WL_WORDS (513 * GBLK)         // 513 rows x 64 g

__global__ __launch_bounds__(512, 1)
void lif_sparse2(const float* __restrict__ spikes,
                 const float* __restrict__ W,
                 float* __restrict__ out)
{
    __shared__ float    Wl[WL_WORDS];                          // 131328 B
    __shared__ __align__(16) unsigned lists[ROWS * 4 * LCAP];  // 16384 B

    const int tid  = threadIdx.x;
    const unsigned lane = tid & 63u;
    const int wav  = tid >> 6;
    const int bid  = blockIdx.x;
    const int bt   = bid & 31;          // b-tile; bid%8 == bt%8 -> same XCD
    const int gb   = bid >> 5;          // 0..7
    const int g0   = gb * GBLK;
    const int row  = bt * ROWS + wav;

    // ---- stage W slice (transposed): Wl[f*64 + gi] = W[g0+gi][f]
    {
        const int gi = tid & 63;
        const int fc = tid >> 6;        // 8 chunks of 64 f
        const float* wrow = W + (size_t)(g0 + gi) * F_DIM + fc * 64;
        #pragma unroll
        for (int u = 0; u < 16; ++u) {
            float4 wv = *(const float4*)(wrow + u * 4);
            const int f = fc * 64 + u * 4;
            Wl[(f + 0) * GBLK + gi] = wv.x;
            Wl[(f + 1) * GBLK + gi] = wv.y;
            Wl[(f + 2) * GBLK + gi] = wv.z;
            Wl[(f + 3) * GBLK + gi] = wv.w;
        }
        if (tid < GBLK) Wl[ZIDX + tid] = 0.f;   // zero row for padding
    }
    __syncthreads();   // the only barrier in the kernel

    unsigned* lb0 = lists + wav * (4 * LCAP);   // current pair: t, t+1
    unsigned* lb1 = lb0 + LCAP;
    unsigned* lb2 = lb0 + 2 * LCAP;             // next pair: t+2, t+3
    unsigned* lb3 = lb0 + 3 * LCAP;

    const size_t rowbase = (size_t)row * F_DIM + lane;
    const unsigned vbase = lane * GBLK;   // word-offset contribution of lane

    float spA[8], spB[8];
    auto loadspA = [&](int t) {
        const float* p = spikes + (size_t)t * BF + rowbase;
        #pragma unroll
        for (int j = 0; j < 8; ++j) spA[j] = p[j * 64];
    };
    auto loadspB = [&](int t) {
        const float* p = spikes + (size_t)t * BF + rowbase;
        #pragma unroll
        for (int j = 0; j < 8; ++j) spB[j] = p[j * 64];
    };

    // decode: rank-compacted scatter of active-f word offsets (f*64); no pad
    auto decode = [&](unsigned* lb, const float* sp) -> int {
        int cnt = 0;
        #pragma unroll
        for (int j = 0; j < 8; ++j) {
            bool act = (__float_as_uint(sp[j]) != 0u);
            unsigned long long m = __ballot(act);
            unsigned rank = __builtin_amdgcn_mbcnt_hi(
                (unsigned)(m >> 32), __builtin_amdgcn_mbcnt_lo((unsigned)m, 0u));
            if (act) lb[cnt + rank] = (unsigned)(j * (64 * GBLK)) + vbase;
            cnt += (int)__popcll(m);
        }
        return cnt;
    };

    // pad both lists of a pair to a common multiple-of-4 entry count
    auto pad2 = [&](unsigned* la, int ca, unsigned* lb, int cb) -> int {
        int m = (ca > cb) ? ca : cb;
        if (m < 4) m = 4;
        const int mc = (m + 3) & ~3;          // target entries
        const int pa = mc - ca;               // 0..~80 (two writes cover 128)
        if ((int)lane < pa)       la[ca + lane]      = ZIDX;
        if ((int)lane + 64 < pa)  la[ca + 64 + lane] = ZIDX;
        const int pb = mc - cb;
        if ((int)lane < pb)       lb[cb + lane]      = ZIDX;
        if ((int)lane + 64 < pb)  lb[cb + 64 + lane] = ZIDX;
        return mc >> 2;                       // chunk count
    };

    struct WV { float a[4]; float b[4]; };
    auto ldw = [&](WV& w, uint4 cA, uint4 cB) {
        w.a[0] = Wl[cA.x + lane]; w.a[1] = Wl[cA.y + lane];
        w.a[2] = Wl[cA.z + lane]; w.a[3] = Wl[cA.w + lane];
        w.b[0] = Wl[cB.x + lane]; w.b[1] = Wl[cB.y + lane];
        w.b[2] = Wl[cB.z + lane]; w.b[3] = Wl[cB.w + lane];
    };

    // dual-stream consume, 3-deep pipeline:
    //   chunk i+1 offsets in flight | W-reads chunk i in flight | acc chunk i-1
    auto consume2 = [&](const unsigned* la, const unsigned* lb, int nch) -> float2 {
        const uint4* chA = (const uint4*)la;
        const uint4* chB = (const uint4*)lb;
        float aA0 = 0.f, aA1 = 0.f, aA2 = 0.f, aA3 = 0.f;
        float aB0 = 0.f, aB1 = 0.f, aB2 = 0.f, aB3 = 0.f;
        auto acc = [&](const WV& w) {
            aA0 += w.a[0]; aA1 += w.a[1]; aA2 += w.a[2]; aA3 += w.a[3];
            aB0 += w.b[0]; aB1 += w.b[1]; aB2 += w.b[2]; aB3 += w.b[3];
        };
        WV w0, w1;
        uint4 cNA = chA[0], cNB = chB[0];
        ldw(w0, cNA, cNB);                 // W chunk 0 in flight
        cNA = chA[1]; cNB = chB[1];        // chunk 1 offsets in flight (safe: LCAP/4=32 chunks)
        int i = 1;
        for (; i + 1 < nch; i += 2) {
            ldw(w1, cNA, cNB);             // W chunk i
            cNA = chA[i + 1]; cNB = chB[i + 1];
            acc(w0);                       // chunk i-1 (waits only on its reads)
            ldw(w0, cNA, cNB);             // W chunk i+1
            cNA = chA[i + 2]; cNB = chB[i + 2];   // i+2 <= nch <= ~24 < 32: in bounds
            acc(w1);
        }
        if (i < nch) { ldw(w1, cNA, cNB); acc(w0); acc(w1); }
        else         { acc(w0); }
        return make_float2((aA0 + aA1) + (aA2 + aA3), (aB0 + aB1) + (aB2 + aB3));
    };

    // ---- LIF state (per lane: b=row, g=g0+lane)
    float v = 0.f, cu = 0.f, zf = 0.f;
    auto lif = [&](float x) {
        float vdec = v + 0.1f * ((0.0f - v) + cu);   // DT*TAU_MEM_INV = 0.1
        float idec = cu - 0.2f * cu;                  // DT*TAU_SYN_INV = 0.2
        bool  spk  = (vdec - 1.0f) > 0.0f;            // heaviside
        zf = spk ? 1.0f : 0.0f;
        v  = spk ? 0.0f : vdec;                       // V_RESET = 0
        cu = idec + x;
    };

    // ---- prologue: lists for (0,1); spike rows (2,3) in regs
    loadspA(0); loadspB(1);
    int c0 = decode(lb0, spA);
    int c1 = decode(lb1, spB);
    int nCur = pad2(lb0, c0, lb1, c1);
    loadspA(2); loadspB(3);

    for (int t = 0; t < T_STEPS; t += 2) {
        // decode next pair (writes drain in-order under current consume)
        int d0 = decode(lb2, spA);
        int d1 = decode(lb3, spB);
        int nNext = pad2(lb2, d0, lb3, d1);
        int ta = t + 4, tb = t + 5;
        loadspA(ta < T_STEPS ? ta : T_STEPS - 1);
        loadspB(tb < T_STEPS ? tb : T_STEPS - 1);

        float2 x = consume2(lb0, lb1, nCur);
        lif(x.x);
        lif(x.y);

        // rotate buffer pairs
        unsigned* s;
        s = lb0; lb0 = lb2; lb2 = s;
        s = lb1; lb1 = lb3; lb3 = s;
        nCur = nNext;
    }

    // ---- epilogue
    const size_t oidx = (size_t)row * F_DIM + g0 + lane;
    out[oidx]          = zf;
    out[BF + oidx]     = v;
    out[2 * BF + oidx] = cu;
}

extern "C" void kernel_launch(void* const* d_in, const int* in_sizes, int n_in,
                              void* d_out, int out_size, void* d_ws, size_t ws_size,
                              hipStream_t stream)
{
    const float* spikes = (const float*)d_in[0];   // [T,B,F] fp32
    const float* W      = (const float*)d_in[1];   // [F,F]   fp32
    float* out          = (float*)d_out;           // [3,B,F] fp32

    lif_sparse2<<<dim3(256), dim3(512), 0, stream>>>(spikes, W, out);
}